// Round 8
// baseline (76.431 us; speedup 1.0000x reference)
//
#include <hip/hip_runtime.h>
#include <math.h>

// Problem constants (match reference)
#define Lp 1024
#define Bp 64
#define Tt 128          // tile rows
#define NTILE 8         // Lp / Tt
#define NPAIR 36        // NTILE*(NTILE+1)/2 triangular tile pairs

typedef float v2f __attribute__((ext_vector_type(2)));

// Force VOP3P packed-fp32 (the backend scalarizes generic vector fp32 IR;
// round-7 cycle accounting matched scalar issue, not pk issue).
static __device__ __forceinline__ v2f pk_add(v2f a, v2f b) {
    v2f d; asm("v_pk_add_f32 %0, %1, %2" : "=v"(d) : "v"(a), "v"(b)); return d;
}
static __device__ __forceinline__ v2f pk_mul(v2f a, v2f b) {
    v2f d; asm("v_pk_mul_f32 %0, %1, %2" : "=v"(d) : "v"(a), "v"(b)); return d;
}
static __device__ __forceinline__ v2f pk_fma(v2f a, v2f b, v2f c) {
    v2f d; asm("v_pk_fma_f32 %0, %1, %2, %3" : "=v"(d) : "v"(a), "v"(b), "v"(c)); return d;
}

// Math: sum_ij mi*mj*(dy-dx)^2 = [sep_x + sep_y] - 2*sum_ij mi*mj*sqrt(d2x*d2y)
// where sep = sum_ij mi*mj*d2 = 2*(nv*Sum m|p|^2 - |Sum m p|^2)  (O(L), exact).
// Main kernel computes ONLY the cross term (7.5 VALU + 1 sqrt per pair after
// pk packing); diagonal-tile blocks also emit the 9 masked row-stats per
// (batch, tile) -> statsbuf (no atomics, every slot written once, so the
// 0xAA-poisoned workspace needs no zeroing).
//
// Layout: i-tile (slot 0) plain SoA; j-tile (slot 1) NEGATED + DUPLICATED
// (nx[2j]=nx[2j+1]=-x) so one ds_read_b64 yields a broadcast pair and the
// i-j subtract becomes pk_add. 2 i-rows ride in one v2f straight from the
// ds_read_b128 subregs (no splat movs).
// NOTE (round 5/6): no per-block __threadfence fusion — agent-scope release
// does an L2 writeback per block on gfx950 (~+30 us). Two launches win.
__global__ __launch_bounds__(256) void drmsd_main(
    const float* __restrict__ x, const float* __restrict__ y,
    float* __restrict__ partials, float* __restrict__ statsbuf)
{
    __shared__ __align__(16) float xs0x[Tt], xs0y[Tt], xs0z[Tt];
    __shared__ __align__(16) float ys0x[Tt], ys0y[Tt], ys0z[Tt];
    __shared__ __align__(16) float ms0[Tt];
    __shared__ __align__(16) float nx1x[2*Tt], nx1y[2*Tt], nx1z[2*Tt];
    __shared__ __align__(16) float ny1x[2*Tt], ny1y[2*Tt], ny1z[2*Tt];
    __shared__ __align__(16) float ms1[Tt];
    __shared__ float red[4];
    __shared__ float sred[2][9];

    const int b = blockIdx.x;      // batch
    const int p = blockIdx.y;      // triangular pair index 0..35

    // decode p -> (ti, tj), ti <= tj
    int ti = 0, base = 0;
    while (p >= base + (NTILE - ti)) { base += (NTILE - ti); ++ti; }
    const int tj = ti + (p - base);

    const int t = threadIdx.x;

    // ---- stage: threads 0-127 -> i-tile (slot 0), 128-255 -> j-tile (slot 1)
    {
        const int r     = t & (Tt - 1);
        const int which = t >> 7;
        const int tile  = which ? tj : ti;
        const int row   = tile * Tt + r;
        const float* px = x + (size_t)row * (Bp * 3) + (size_t)b * 3;
        const float* py = y + (size_t)row * (Bp * 3) + (size_t)b * 3;
        const float x0 = px[0], x1 = px[1], x2 = px[2];
        const float y0 = py[0], y1 = py[1], y2 = py[2];
        const float m  = ((y0 + y1 + y2) != 0.0f) ? 1.0f : 0.0f;
        if (which) {
            const int rd = r << 1;
            nx1x[rd] = -x0; nx1x[rd+1] = -x0;
            nx1y[rd] = -x1; nx1y[rd+1] = -x1;
            nx1z[rd] = -x2; nx1z[rd+1] = -x2;
            ny1x[rd] = -y0; ny1x[rd+1] = -y0;
            ny1y[rd] = -y1; ny1y[rd+1] = -y1;
            ny1z[rd] = -y2; ny1z[rd+1] = -y2;
            ms1[r] = m;
        } else {
            xs0x[r] = x0; xs0y[r] = x1; xs0z[r] = x2;
            ys0x[r] = y0; ys0y[r] = y1; ys0z[r] = y2;
            ms0[r] = m;
        }
        // ---- per-(b,tile) masked stats, diagonal blocks only (covers every
        // (b,row) exactly once across the grid)
        if (ti == tj && !which) {      // t < 128: waves 0,1 fully active
            float c[9];
            c[0] = m;
            c[1] = m * (x0*x0 + x1*x1 + x2*x2);
            c[2] = m * x0; c[3] = m * x1; c[4] = m * x2;
            c[5] = m * (y0*y0 + y1*y1 + y2*y2);
            c[6] = m * y0; c[7] = m * y1; c[8] = m * y2;
#pragma unroll
            for (int k = 0; k < 9; ++k) {
                float v = c[k];
#pragma unroll
                for (int off = 32; off > 0; off >>= 1)
                    v += __shfl_down(v, off, 64);
                c[k] = v;
            }
            if ((t & 63) == 0) {
#pragma unroll
                for (int k = 0; k < 9; ++k) sred[t >> 6][k] = c[k];
            }
        }
    }
    __syncthreads();

    if (ti == tj && t == 0) {
        float* sb = statsbuf + ((size_t)b * NTILE + ti) * 9;
#pragma unroll
        for (int k = 0; k < 9; ++k) sb[k] = sred[0][k] + sred[1][k];
    }

    const int jsl = (t & 7) << 2;    // 4 j cols per jj step: jsl..jsl+3
    const int rg  = t >> 3;          // 0..31
    const int i0  = rg << 2;         // i-rows i0..i0+3
    const int wv  = t >> 6;          // wave id

    // i-row packs: 2 rows per v2f, free subregs of the b128 loads
    const float4 fxx = *(const float4*)&xs0x[i0];
    const float4 fxy = *(const float4*)&xs0y[i0];
    const float4 fxz = *(const float4*)&xs0z[i0];
    const float4 fyx = *(const float4*)&ys0x[i0];
    const float4 fyy = *(const float4*)&ys0y[i0];
    const float4 fyz = *(const float4*)&ys0z[i0];
    const float4 fmi = *(const float4*)&ms0[i0];
    v2f Ax[2], Ay[2], Az[2], Bx[2], By[2], Bz[2];
    Ax[0] = (v2f){fxx.x, fxx.y}; Ax[1] = (v2f){fxx.z, fxx.w};
    Ay[0] = (v2f){fxy.x, fxy.y}; Ay[1] = (v2f){fxy.z, fxy.w};
    Az[0] = (v2f){fxz.x, fxz.y}; Az[1] = (v2f){fxz.z, fxz.w};
    Bx[0] = (v2f){fyx.x, fyx.y}; Bx[1] = (v2f){fyx.z, fyx.w};
    By[0] = (v2f){fyy.x, fyy.y}; By[1] = (v2f){fyy.z, fyy.w};
    Bz[0] = (v2f){fyz.x, fyz.y}; Bz[1] = (v2f){fyz.z, fyz.w};

    float acc[4] = {0.f, 0.f, 0.f, 0.f};

#pragma unroll
    for (int jj = 0; jj < 4; ++jj) {
#pragma unroll
        for (int c = 0; c < 4; ++c) {
            const int j  = jj * 32 + jsl + c;
            const int jd = j << 1;
            const v2f njx = *(const v2f*)&nx1x[jd];
            const v2f njy = *(const v2f*)&nx1y[jd];
            const v2f njz = *(const v2f*)&nx1z[jd];
            const v2f mjx = *(const v2f*)&ny1x[jd];
            const v2f mjy = *(const v2f*)&ny1y[jd];
            const v2f mjz = *(const v2f*)&ny1z[jd];
            const float mj = ms1[j];
#pragma unroll
            for (int rp = 0; rp < 2; ++rp) {
                const v2f ax = pk_add(Ax[rp], njx);     // xi - xj (j negated)
                const v2f ay = pk_add(Ay[rp], njy);
                const v2f az = pk_add(Az[rp], njz);
                const v2f d2x = pk_fma(ax, ax, pk_fma(ay, ay, pk_mul(az, az)));
                const v2f bx = pk_add(Bx[rp], mjx);
                const v2f by = pk_add(By[rp], mjy);
                const v2f bz = pk_add(Bz[rp], mjz);
                const v2f d2y = pk_fma(bx, bx, pk_fma(by, by, pk_mul(bz, bz)));
                const v2f pr = pk_mul(d2x, d2y);        // >= 0 exactly
                const float s0 = __builtin_amdgcn_sqrtf(pr.x);
                const float s1 = __builtin_amdgcn_sqrtf(pr.y);
                acc[rp*2]   = fmaf(mj, s0, acc[rp*2]);
                acc[rp*2+1] = fmaf(mj, s1, acc[rp*2+1]);
            }
        }
    }

    // row mask epilogue
    const float mir[4] = { fmi.x, fmi.y, fmi.z, fmi.w };
    float total = 0.0f;
#pragma unroll
    for (int r = 0; r < 4; ++r) total = fmaf(acc[r], mir[r], total);

    // ---- block reduction ----
#pragma unroll
    for (int off = 32; off > 0; off >>= 1)
        total += __shfl_down(total, off, 64);
    if ((t & 63) == 0) red[wv] = total;
    __syncthreads();
    if (t == 0) {
        float s = red[0] + red[1] + red[2] + red[3];
        if (ti != tj) s *= 2.0f;   // off-diagonal pair counted for both orders
        partials[(size_t)p * Bp + b] = s;   // [p][b] -> coalesced final reads
    }
}

__global__ __launch_bounds__(256) void drmsd_final(
    const float* __restrict__ partials, const float* __restrict__ statsbuf,
    float* __restrict__ out)
{
    __shared__ float sums[256];
    const int t    = threadIdx.x;
    const int lane = t & 63;
    const int q    = t >> 6;       // wave q handles 9 p's
    float s = 0.0f;
#pragma unroll
    for (int k = 0; k < 9; ++k) {
        const int pidx = q * 9 + k;
        s += partials[(size_t)pidx * Bp + lane];   // coalesced across lanes
    }
    sums[t] = s;
    __syncthreads();
    if (t < 64) {
        const int bb = t;
        const float cross = sums[t] + sums[t + 64] + sums[t + 128] + sums[t + 192];
        float st[9] = {0.f,0.f,0.f,0.f,0.f,0.f,0.f,0.f,0.f};
#pragma unroll
        for (int tile = 0; tile < NTILE; ++tile) {
            const float* sb = statsbuf + ((size_t)bb * NTILE + tile) * 9;
#pragma unroll
            for (int k = 0; k < 9; ++k) st[k] += sb[k];
        }
        const float nv  = st[0];
        const float sepx = 2.0f * (nv * st[1] - (st[2]*st[2] + st[3]*st[3] + st[4]*st[4]));
        const float sepy = 2.0f * (nv * st[5] - (st[6]*st[6] + st[7]*st[7] + st[8]*st[8]));
        const float Sb = fmaxf(sepx + sepy - 2.0f * cross, 0.0f);
        float pb = sqrtf(Sb);
#pragma unroll
        for (int off = 32; off > 0; off >>= 1)
            pb += __shfl_down(pb, off, 64);
        if (t == 0) {
            const double denom = sqrt((double)Lp * (double)Lp / 2.0 - (double)Lp);
            out[0] = (float)((double)pb / denom / (double)Bp);
        }
    }
}

extern "C" void kernel_launch(void* const* d_in, const int* in_sizes, int n_in,
                              void* d_out, int out_size, void* d_ws, size_t ws_size,
                              hipStream_t stream) {
    const float* x = (const float*)d_in[0];
    const float* y = (const float*)d_in[1];
    float* out      = (float*)d_out;
    float* partials = (float*)d_ws;                        // 36*64 floats = 9216 B
    float* statsbuf = (float*)((char*)d_ws + 9216);        // 64*8*9 floats = 18432 B

    dim3 grid(Bp, NPAIR);
    drmsd_main<<<grid, 256, 0, stream>>>(x, y, partials, statsbuf);
    drmsd_final<<<1, 256, 0, stream>>>(partials, statsbuf, out);
}